// Round 5
// baseline (585.452 us; speedup 1.0000x reference)
//
#include <hip/hip_runtime.h>
#include <hip/hip_bf16.h>
#include <cstdint>
#include <cstddef>

typedef __fp16 f16_t;
typedef __attribute__((ext_vector_type(8))) __fp16 f16x8;
typedef __attribute__((ext_vector_type(4))) __fp16 f16x4;
typedef __attribute__((ext_vector_type(2))) __fp16 h2_t;
typedef __attribute__((ext_vector_type(4))) float floatx4;

// ---------------------------------------------------------------- helpers
__device__ __forceinline__ void async_copy_16B(const void* g, void* l) {
  __builtin_amdgcn_global_load_lds(
      (const __attribute__((address_space(1))) void*)g,
      (__attribute__((address_space(3))) void*)l, 16, 0, 0);
}

// ---------------------------------------------------------------- prep
// Fused: cast x/w_in/w_out to f16 (5242880 float4s) and build packed f16
// weight-pair table wp[p][c], p=0..127:
//   p<126 : (w[p], w[p+1]) ; p==126 : (w[126], 0) ; p==127 : (0, w[0])
__global__ __launch_bounds__(256) void prep(
    const float* __restrict__ x, const float* __restrict__ w_in,
    const float* __restrict__ w_out, const float* __restrict__ w_dw,
    f16_t* __restrict__ x_h, f16_t* __restrict__ wi_h,
    f16_t* __restrict__ wo_h, h2_t* __restrict__ wp) {
  const int tid = blockIdx.x * 256 + threadIdx.x;
  if (tid < 5242880) {
    const float* src;
    f16_t* dst;
    int off;
    if (tid < 2097152) {
      src = x; dst = x_h; off = tid;
    } else if (tid < 4194304) {
      src = w_in; dst = wi_h; off = tid - 2097152;
    } else {
      src = w_out; dst = wo_h; off = tid - 4194304;
    }
    const float4 v = *(const float4*)(src + (size_t)off * 4);
    f16x4 o;
    o.x = (f16_t)v.x; o.y = (f16_t)v.y; o.z = (f16_t)v.z; o.w = (f16_t)v.w;
    *(f16x4*)(dst + (size_t)off * 4) = o;
  } else {
    const int idx = tid - 5242880;
    if (idx < 128 * 4096) {
      const int p = idx >> 12;
      const int c = idx & 4095;
      float a, b;
      if (p < 126) {
        a = w_dw[c * 127 + p]; b = w_dw[c * 127 + p + 1];
      } else if (p == 126) {
        a = w_dw[c * 127 + 126]; b = 0.f;
      } else {
        a = 0.f; b = w_dw[c * 127 + 0];
      }
      h2_t w;
      w.x = (f16_t)a; w.y = (f16_t)b;
      wp[idx] = w;
    }
  }
}

// ---------------------------------------------------------------- GEMM (NT)
// C[M,N] = A[M,K] * B[N,K]^T ; A,B f16 row-major, C = OutT row-major.
// BM=128 rows, BN_ in {128,64}, BK=64 as two 32-col LDS panels.
template <int BN_, typename OutT>
__global__ __launch_bounds__(256) void gemm_bt64(
    const f16_t* __restrict__ A, const f16_t* __restrict__ B,
    OutT* __restrict__ C, int M, int N, int K) {
  constexpr int BM_ = 128;
  constexpr int FI = (BN_ == 128) ? 4 : 2;
  constexpr int FJ = 4;
  constexpr int ACH = BM_ * 8;
  constexpr int CH = (BM_ + BN_) * 8;
  constexpr int CPT = CH / 256;

  __shared__ f16_t smem[(BM_ + BN_) * 64];
  f16_t* const As0 = smem;
  f16_t* const As1 = smem + BM_ * 32;
  f16_t* const Bs0 = smem + BM_ * 64;
  f16_t* const Bs1 = smem + BM_ * 64 + BN_ * 32;

  const int t = threadIdx.x;
  const int lane = t & 63;
  const int wave = t >> 6;
  const int m0 = blockIdx.y * BM_;
  const int n0 = blockIdx.x * BN_;
  const int wr = (BN_ == 128) ? (wave >> 1) * 64 : wave * 32;
  const int wc = (BN_ == 128) ? (wave & 1) * 64 : 0;
  const int fr = lane & 15;
  const int fk = (lane >> 4) * 8;

  floatx4 acc[FI][FJ] = {};

  const int kTiles = K / 64;
  for (int kt = 0; kt < kTiles; ++kt) {
    const int k0 = kt * 64;
    __syncthreads();
#pragma unroll
    for (int it = 0; it < CPT; ++it) {
      const int p = it * 256 + t;
      const f16_t* gsrc;
      if (p < BM_ * 4) {
        const int row = p >> 2, kc = (p & 3) * 8;
        gsrc = A + (size_t)(m0 + row) * K + k0 + kc;
      } else if (p < ACH) {
        const int q = p - BM_ * 4;
        const int row = q >> 2, kc = 32 + (q & 3) * 8;
        gsrc = A + (size_t)(m0 + row) * K + k0 + kc;
      } else if (p < ACH + BN_ * 4) {
        const int q = p - ACH;
        const int row = q >> 2, kc = (q & 3) * 8;
        gsrc = B + (size_t)(n0 + row) * K + k0 + kc;
      } else {
        const int q = p - ACH - BN_ * 4;
        const int row = q >> 2, kc = 32 + (q & 3) * 8;
        gsrc = B + (size_t)(n0 + row) * K + k0 + kc;
      }
      async_copy_16B(gsrc, smem + p * 8);
    }
    __syncthreads();

    f16x8 af[FI][2], bfr[FJ][2];
#pragma unroll
    for (int i = 0; i < FI; ++i) {
      const int r = (wr + i * 16 + fr) * 32 + fk;
      af[i][0] = *(const f16x8*)(As0 + r);
      af[i][1] = *(const f16x8*)(As1 + r);
    }
#pragma unroll
    for (int j = 0; j < FJ; ++j) {
      const int r = (wc + j * 16 + fr) * 32 + fk;
      bfr[j][0] = *(const f16x8*)(Bs0 + r);
      bfr[j][1] = *(const f16x8*)(Bs1 + r);
    }
#pragma unroll
    for (int h = 0; h < 2; ++h)
#pragma unroll
      for (int i = 0; i < FI; ++i)
#pragma unroll
        for (int j = 0; j < FJ; ++j)
          acc[i][j] = __builtin_amdgcn_mfma_f32_16x16x32_f16(
              af[i][h], bfr[j][h], acc[i][j], 0, 0, 0);
  }

  // C/D layout: col = lane&15, row = (lane>>4)*4 + reg
  const int cr = (lane >> 4) * 4;
  const int cc = lane & 15;
#pragma unroll
  for (int i = 0; i < FI; ++i)
#pragma unroll
    for (int j = 0; j < FJ; ++j)
#pragma unroll
      for (int r = 0; r < 4; ++r) {
        const int row = m0 + wr + i * 16 + cr + r;
        const int col = n0 + wc + j * 16 + cc;
        C[(size_t)row * N + col] = (OutT)acc[i][j][r];
      }
}

// ---------------------------------------------------------------- conv+gate
// vg: [8192][8192] f16 (v = cols 0..4095, g = cols 4096..8191)
// wp: [128][4096] packed f16 weight pairs ; y: [8192][4096] f16
// Block: 64 channels x 128 l-outputs; 4 waves x 32 l's each, lane=channel.
// v_dot2_f32_f16 (2 MACs/inst) with 17-slot packed-pair ring; tap-parity
// trick keeps every v-pair even-aligned. No launch_bounds (R4 lesson:
// forcing occupancy made the compiler spill 220MB to scratch).
#define CONV_L 128
#define CROWS 254  // 128 + 126 history rows

__global__ __launch_bounds__(256) void conv_gate(
    const f16_t* __restrict__ vg, const h2_t* __restrict__ wp,
    const float* __restrict__ b_dw, f16_t* __restrict__ y) {
  __shared__ f16_t vt[CROWS * 64];
  const int t = threadIdx.x;
  const int lane = t & 63;
  const int wave = t >> 6;
  const int c0 = blockIdx.x * 64;
  const int lt = blockIdx.y & 31;   // 4096/128 = 32 l-tiles
  const int b = blockIdx.y >> 5;
  const int l0 = lt * CONV_L;

  // stage v tile rows [l0-126, l0+127] x 64 channels (zeros for l<0)
  for (int chunk = t; chunk < CROWS * 8; chunk += 256) {
    const int row = chunk >> 3;
    const int cc = (chunk & 7) * 8;
    const int l = l0 - 126 + row;
    uint4* dst = (uint4*)(vt + row * 64 + cc);
    if (l < 0) {
      *dst = make_uint4(0u, 0u, 0u, 0u);
    } else {
      *dst = *(const uint4*)(vg + (size_t)(b * 4096 + l) * 8192 + c0 + cc);
    }
  }
  __syncthreads();

  const int c = c0 + lane;
  const int r0 = wave * 32;  // tile row of v[lb-126]
  const float bias = b_dw[c];
  float acc[32];
#pragma unroll
  for (int i = 0; i < 32; ++i) acc[i] = bias;

  // ring slot m holds pair p=2m: (v[r0+2m], v[r0+2m+1]); init m=0..16
  h2_t ring[17];
#pragma unroll
  for (int m = 0; m < 17; ++m) {
    h2_t pr;
    pr.x = vt[(r0 + 2 * m) * 64 + lane];
    pr.y = vt[(r0 + 2 * m + 1) * 64 + lane];
    ring[m] = pr;
  }

  const h2_t* wpc = wp + c;
  // tap 0 for odd outputs: weight (0, w[0]) = wp[127]
  {
    const h2_t w0 = wpc[127 * 4096];
#pragma unroll
    for (int h = 0; h < 16; ++h)
      acc[2 * h + 1] =
          __builtin_amdgcn_fdot2(w0, ring[h], acc[2 * h + 1], false);
  }

  // main: step k: even outs use wp[2k] (taps 2k,2k+1); odd outs use wp[2k+1]
#pragma unroll
  for (int k = 0; k < 64; ++k) {
    const h2_t we = wpc[(size_t)(2 * k) * 4096];
#pragma unroll
    for (int h = 0; h < 16; ++h)
      acc[2 * h] =
          __builtin_amdgcn_fdot2(we, ring[(k + h) % 17], acc[2 * h], false);
    if (k < 63) {
      const h2_t wo = wpc[(size_t)(2 * k + 1) * 4096];
#pragma unroll
      for (int h = 0; h < 16; ++h)
        acc[2 * h + 1] = __builtin_amdgcn_fdot2(wo, ring[(k + 1 + h) % 17],
                                                acc[2 * h + 1], false);
      if (k < 62) {  // slide: slot k%17 <- pair p=2k+34
        h2_t np;
        np.x = vt[(r0 + 2 * k + 34) * 64 + lane];
        np.y = vt[(r0 + 2 * k + 35) * 64 + lane];
        ring[k % 17] = np;
      }
    }
  }

  const int lb = l0 + r0;
  const f16_t* gp = vg + (size_t)(b * 4096 + lb) * 8192 + 4096 + c;
  f16_t* yp = y + (size_t)(b * 4096 + lb) * 4096 + c;
#pragma unroll
  for (int i = 0; i < 32; ++i) {
    const float gv = (float)gp[(size_t)i * 8192];
    const float v = acc[i];
    const float sv = v / (1.f + __expf(-v));
    const float sg = gv / (1.f + __expf(-gv));
    yp[(size_t)i * 4096] = (f16_t)(sv * sg);
  }
}

// ---------------------------------------------------------------- launch
extern "C" void kernel_launch(void* const* d_in, const int* in_sizes, int n_in,
                              void* d_out, int out_size, void* d_ws,
                              size_t ws_size, hipStream_t stream) {
  const float* x     = (const float*)d_in[0];  // [2,4096,1024]
  const float* w_in  = (const float*)d_in[1];  // [8192,1024]
  const float* w_dw  = (const float*)d_in[2];  // [4096,127]
  const float* b_dw  = (const float*)d_in[3];  // [4096]
  const float* w_out = (const float*)d_in[4];  // [1024,4096]
  float* out = (float*)d_out;                  // [2,4096,1024]

  char* p = (char*)d_ws;
  f16_t* x_h  = (f16_t*)p; p += (size_t)8192 * 1024 * 2;
  f16_t* wi_h = (f16_t*)p; p += (size_t)8192 * 1024 * 2;
  f16_t* wo_h = (f16_t*)p; p += (size_t)1024 * 4096 * 2;
  h2_t*  wp   = (h2_t*)p;  p += (size_t)128 * 4096 * 4;
  f16_t* vg   = (f16_t*)p; p += (size_t)8192 * 8192 * 2;
  f16_t* y    = (f16_t*)p; p += (size_t)8192 * 4096 * 2;

  // fused casts + packed weight-pair build: (5242880 + 524288)/256 blocks
  prep<<<22528, 256, 0, stream>>>(x, w_in, w_out, w_dw, x_h, wi_h, wo_h, wp);

  // vg[8192,8192] = x[8192,1024] @ w_in[8192,1024]^T
  gemm_bt64<128, f16_t><<<dim3(64, 64), 256, 0, stream>>>(x_h, wi_h, vg,
                                                          8192, 8192, 1024);
  // y = silu(causal_dwconv(v)+b) * silu(g)
  conv_gate<<<dim3(64, 64), 256, 0, stream>>>(vg, wp, b_dw, y);
  // out[8192,1024] = y[8192,4096] @ w_out[1024,4096]^T (128x64 tiles, 4/CU)
  gemm_bt64<64, float><<<dim3(16, 64), 256, 0, stream>>>(y, wo_h, out,
                                                         8192, 1024, 4096);
}

// Round 6
// 506.392 us; speedup vs baseline: 1.1561x; 1.1561x over previous
//
#include <hip/hip_runtime.h>
#include <hip/hip_bf16.h>
#include <cstdint>
#include <cstddef>

typedef __fp16 f16_t;
typedef __attribute__((ext_vector_type(8))) __fp16 f16x8;
typedef __attribute__((ext_vector_type(4))) __fp16 f16x4;
typedef __attribute__((ext_vector_type(2))) __fp16 h2_t;
typedef __attribute__((ext_vector_type(4))) float floatx4;

// ---------------------------------------------------------------- helpers
__device__ __forceinline__ void async_copy_16B(const void* g, void* l) {
  __builtin_amdgcn_global_load_lds(
      (const __attribute__((address_space(1))) void*)g,
      (__attribute__((address_space(3))) void*)l, 16, 0, 0);
}

// ---------------------------------------------------------------- prep
// Fused: cast x/w_in/w_out to f16 (5242880 float4s) and build packed f16
// weight-pair table wp[p][c], p=0..127:
//   p<126 : (w[p], w[p+1]) ; p==126 : (w[126], 0) ; p==127 : (0, w[0])
__global__ __launch_bounds__(256) void prep(
    const float* __restrict__ x, const float* __restrict__ w_in,
    const float* __restrict__ w_out, const float* __restrict__ w_dw,
    f16_t* __restrict__ x_h, f16_t* __restrict__ wi_h,
    f16_t* __restrict__ wo_h, h2_t* __restrict__ wp) {
  const int tid = blockIdx.x * 256 + threadIdx.x;
  if (tid < 5242880) {
    const float* src;
    f16_t* dst;
    int off;
    if (tid < 2097152) {
      src = x; dst = x_h; off = tid;
    } else if (tid < 4194304) {
      src = w_in; dst = wi_h; off = tid - 2097152;
    } else {
      src = w_out; dst = wo_h; off = tid - 4194304;
    }
    const float4 v = *(const float4*)(src + (size_t)off * 4);
    f16x4 o;
    o.x = (f16_t)v.x; o.y = (f16_t)v.y; o.z = (f16_t)v.z; o.w = (f16_t)v.w;
    *(f16x4*)(dst + (size_t)off * 4) = o;
  } else {
    const int idx = tid - 5242880;
    if (idx < 128 * 4096) {
      const int p = idx >> 12;
      const int c = idx & 4095;
      float a, b;
      if (p < 126) {
        a = w_dw[c * 127 + p]; b = w_dw[c * 127 + p + 1];
      } else if (p == 126) {
        a = w_dw[c * 127 + 126]; b = 0.f;
      } else {
        a = 0.f; b = w_dw[c * 127 + 0];
      }
      h2_t w;
      w.x = (f16_t)a; w.y = (f16_t)b;
      wp[idx] = w;
    }
  }
}

// ---------------------------------------------------------------- GEMM (NT)
// C[M,N] = A[M,K] * B[N,K]^T ; A,B f16 row-major, C = OutT row-major.
// BM=128 rows, BN_ in {128,64}, BK=64 as two 32-col LDS panels.
template <int BN_, typename OutT>
__global__ __launch_bounds__(256) void gemm_bt64(
    const f16_t* __restrict__ A, const f16_t* __restrict__ B,
    OutT* __restrict__ C, int M, int N, int K) {
  constexpr int BM_ = 128;
  constexpr int FI = (BN_ == 128) ? 4 : 2;
  constexpr int FJ = 4;
  constexpr int ACH = BM_ * 8;
  constexpr int CH = (BM_ + BN_) * 8;
  constexpr int CPT = CH / 256;

  __shared__ f16_t smem[(BM_ + BN_) * 64];
  f16_t* const As0 = smem;
  f16_t* const As1 = smem + BM_ * 32;
  f16_t* const Bs0 = smem + BM_ * 64;
  f16_t* const Bs1 = smem + BM_ * 64 + BN_ * 32;

  const int t = threadIdx.x;
  const int lane = t & 63;
  const int wave = t >> 6;
  const int m0 = blockIdx.y * BM_;
  const int n0 = blockIdx.x * BN_;
  const int wr = (BN_ == 128) ? (wave >> 1) * 64 : wave * 32;
  const int wc = (BN_ == 128) ? (wave & 1) * 64 : 0;
  const int fr = lane & 15;
  const int fk = (lane >> 4) * 8;

  floatx4 acc[FI][FJ] = {};

  const int kTiles = K / 64;
  for (int kt = 0; kt < kTiles; ++kt) {
    const int k0 = kt * 64;
    __syncthreads();
#pragma unroll
    for (int it = 0; it < CPT; ++it) {
      const int p = it * 256 + t;
      const f16_t* gsrc;
      if (p < BM_ * 4) {
        const int row = p >> 2, kc = (p & 3) * 8;
        gsrc = A + (size_t)(m0 + row) * K + k0 + kc;
      } else if (p < ACH) {
        const int q = p - BM_ * 4;
        const int row = q >> 2, kc = 32 + (q & 3) * 8;
        gsrc = A + (size_t)(m0 + row) * K + k0 + kc;
      } else if (p < ACH + BN_ * 4) {
        const int q = p - ACH;
        const int row = q >> 2, kc = (q & 3) * 8;
        gsrc = B + (size_t)(n0 + row) * K + k0 + kc;
      } else {
        const int q = p - ACH - BN_ * 4;
        const int row = q >> 2, kc = 32 + (q & 3) * 8;
        gsrc = B + (size_t)(n0 + row) * K + k0 + kc;
      }
      async_copy_16B(gsrc, smem + p * 8);
    }
    __syncthreads();

    f16x8 af[FI][2], bfr[FJ][2];
#pragma unroll
    for (int i = 0; i < FI; ++i) {
      const int r = (wr + i * 16 + fr) * 32 + fk;
      af[i][0] = *(const f16x8*)(As0 + r);
      af[i][1] = *(const f16x8*)(As1 + r);
    }
#pragma unroll
    for (int j = 0; j < FJ; ++j) {
      const int r = (wc + j * 16 + fr) * 32 + fk;
      bfr[j][0] = *(const f16x8*)(Bs0 + r);
      bfr[j][1] = *(const f16x8*)(Bs1 + r);
    }
#pragma unroll
    for (int h = 0; h < 2; ++h)
#pragma unroll
      for (int i = 0; i < FI; ++i)
#pragma unroll
        for (int j = 0; j < FJ; ++j)
          acc[i][j] = __builtin_amdgcn_mfma_f32_16x16x32_f16(
              af[i][h], bfr[j][h], acc[i][j], 0, 0, 0);
  }

  // C/D layout: col = lane&15, row = (lane>>4)*4 + reg
  const int cr = (lane >> 4) * 4;
  const int cc = lane & 15;
#pragma unroll
  for (int i = 0; i < FI; ++i)
#pragma unroll
    for (int j = 0; j < FJ; ++j)
#pragma unroll
      for (int r = 0; r < 4; ++r) {
        const int row = m0 + wr + i * 16 + cr + r;
        const int col = n0 + wc + j * 16 + cc;
        C[(size_t)row * N + col] = (OutT)acc[i][j][r];
      }
}

// ---------------------------------------------------------------- conv+gate
// vg: [8192][8192] f16 (v = cols 0..4095, g = cols 4096..8191)
// wp: [128][4096] packed f16 weight pairs ; y: [8192][4096] f16
// Block: 64 channels x 128 l-outputs; 4 waves x 32 l's, lane=channel.
// All operands LDS-resident with immediate ds offsets (R5 lesson: global
// weight loads per tap -> 136 VGPR of pipelined loads -> 11% occupancy).
// vtp holds v h2-interleaved: word m = (v[2m], v[2m+1]) -> ring slide is one
// ds_read_b32. Tap-parity keeps every fdot2 v-operand pair-aligned.
#define CONV_L 128
#define CPAIRS 127  // (CONV_L + 126) / 2

__global__ __launch_bounds__(256) void conv_gate(
    const f16_t* __restrict__ vg, const h2_t* __restrict__ wp,
    const float* __restrict__ b_dw, f16_t* __restrict__ y) {
  __shared__ uint32_t vtp[CPAIRS * 64];  // 32.5 KB
  __shared__ uint32_t wpl[128 * 64];     // 32 KB
  const int t = threadIdx.x;
  const int lane = t & 63;
  const int wave = t >> 6;
  const int c0 = blockIdx.x * 64;
  const int lt = blockIdx.y & 31;   // 4096/128 l-tiles
  const int b = blockIdx.y >> 5;
  const int l0 = lt * CONV_L;

  // stage weight pairs wp[p][c0..c0+63] -> wpl via global->LDS DMA
#pragma unroll
  for (int it = 0; it < 8; ++it) {
    const int q = it * 256 + t;  // 2048 16B chunks: row = q>>4, 4 words each
    async_copy_16B(wp + (size_t)(q >> 4) * 4096 + c0 + (q & 15) * 4,
                   wpl + q * 4);
  }
  // stage v rows [l0-126, l0+127] pair-interleaved (zeros for l<0)
  for (int q = t; q < CPAIRS * 8; q += 256) {
    const int m = q >> 3;
    const int oc = (q & 7) * 8;
    const int le = l0 - 126 + 2 * m;  // always even
    uint4 a = make_uint4(0u, 0u, 0u, 0u);
    uint4 bb = make_uint4(0u, 0u, 0u, 0u);
    if (le >= 0) {
      const size_t base = (size_t)(b * 4096 + le) * 8192 + c0 + oc;
      a = *(const uint4*)(vg + base);
      bb = *(const uint4*)(vg + base + 8192);
    }
    uint32_t* dst = vtp + m * 64 + oc;
    const uint32_t aw[4] = {a.x, a.y, a.z, a.w};
    const uint32_t bw[4] = {bb.x, bb.y, bb.z, bb.w};
#pragma unroll
    for (int i = 0; i < 4; ++i) {
      dst[2 * i] = (aw[i] & 0xFFFFu) | (bw[i] << 16);
      dst[2 * i + 1] = (aw[i] >> 16) | (bw[i] & 0xFFFF0000u);
    }
  }
  __syncthreads();

  const int c = c0 + lane;
  const float bias = b_dw[c];
  float acc[32];
#pragma unroll
  for (int i = 0; i < 32; ++i) acc[i] = bias;

  // single-base immediate-offset LDS pointers
  const uint32_t* vbase = vtp + wave * 16 * 64 + lane;  // pair index of v[r0]
  const uint32_t* wbase = wpl + lane;

  // ring slot m holds pair (v[r0+2m], v[r0+2m+1]); slots 0..16
  h2_t ring[17];
#pragma unroll
  for (int m = 0; m < 17; ++m)
    ring[m] = __builtin_bit_cast(h2_t, vbase[m * 64]);

  // tap 0 for odd outputs: weight (0, w[0]) = wpl row 127
  {
    const h2_t w0 = __builtin_bit_cast(h2_t, wbase[127 * 64]);
#pragma unroll
    for (int h = 0; h < 16; ++h)
      acc[2 * h + 1] =
          __builtin_amdgcn_fdot2(w0, ring[h], acc[2 * h + 1], false);
  }

  // step k: even outs use row 2k (taps 2k,2k+1); odd outs row 2k+1
#pragma unroll
  for (int k = 0; k < 64; ++k) {
    const h2_t we = __builtin_bit_cast(h2_t, wbase[(2 * k) * 64]);
#pragma unroll
    for (int h = 0; h < 16; ++h)
      acc[2 * h] =
          __builtin_amdgcn_fdot2(we, ring[(k + h) % 17], acc[2 * h], false);
    if (k < 63) {
      const h2_t wo = __builtin_bit_cast(h2_t, wbase[(2 * k + 1) * 64]);
#pragma unroll
      for (int h = 0; h < 16; ++h)
        acc[2 * h + 1] = __builtin_amdgcn_fdot2(wo, ring[(k + 1 + h) % 17],
                                                acc[2 * h + 1], false);
      if (k < 62)  // slide: slot k%17 <- pair k+17
        ring[k % 17] = __builtin_bit_cast(h2_t, vbase[(17 + k) * 64]);
    }
  }

  const int lb = l0 + wave * 32;
  const f16_t* gp = vg + (size_t)(b * 4096 + lb) * 8192 + 4096 + c;
  f16_t* yp = y + (size_t)(b * 4096 + lb) * 4096 + c;
#pragma unroll
  for (int i = 0; i < 32; ++i) {
    const float gv = (float)gp[(size_t)i * 8192];
    const float v = acc[i];
    const float sv = v / (1.f + __expf(-v));
    const float sg = gv / (1.f + __expf(-gv));
    yp[(size_t)i * 4096] = (f16_t)(sv * sg);
  }
}

// ---------------------------------------------------------------- launch
extern "C" void kernel_launch(void* const* d_in, const int* in_sizes, int n_in,
                              void* d_out, int out_size, void* d_ws,
                              size_t ws_size, hipStream_t stream) {
  const float* x     = (const float*)d_in[0];  // [2,4096,1024]
  const float* w_in  = (const float*)d_in[1];  // [8192,1024]
  const float* w_dw  = (const float*)d_in[2];  // [4096,127]
  const float* b_dw  = (const float*)d_in[3];  // [4096]
  const float* w_out = (const float*)d_in[4];  // [1024,4096]
  float* out = (float*)d_out;                  // [2,4096,1024]

  char* p = (char*)d_ws;
  f16_t* x_h  = (f16_t*)p; p += (size_t)8192 * 1024 * 2;
  f16_t* wi_h = (f16_t*)p; p += (size_t)8192 * 1024 * 2;
  f16_t* wo_h = (f16_t*)p; p += (size_t)1024 * 4096 * 2;
  h2_t*  wp   = (h2_t*)p;  p += (size_t)128 * 4096 * 4;
  f16_t* vg   = (f16_t*)p; p += (size_t)8192 * 8192 * 2;
  f16_t* y    = (f16_t*)p; p += (size_t)8192 * 4096 * 2;

  // fused casts + packed weight-pair build
  prep<<<22528, 256, 0, stream>>>(x, w_in, w_out, w_dw, x_h, wi_h, wo_h, wp);

  // vg[8192,8192] = x[8192,1024] @ w_in[8192,1024]^T
  gemm_bt64<128, f16_t><<<dim3(64, 64), 256, 0, stream>>>(x_h, wi_h, vg,
                                                          8192, 8192, 1024);
  // y = silu(causal_dwconv(v)+b) * silu(g)
  conv_gate<<<dim3(64, 64), 256, 0, stream>>>(vg, wp, b_dw, y);
  // out[8192,1024] = y[8192,4096] @ w_out[1024,4096]^T (128x64 tiles, 4/CU)
  gemm_bt64<64, float><<<dim3(16, 64), 256, 0, stream>>>(y, wo_h, out,
                                                         8192, 1024, 4096);
}

// Round 7
// 488.009 us; speedup vs baseline: 1.1997x; 1.0377x over previous
//
#include <hip/hip_runtime.h>
#include <hip/hip_bf16.h>
#include <cstdint>
#include <cstddef>

typedef __fp16 f16_t;
typedef __attribute__((ext_vector_type(8))) __fp16 f16x8;
typedef __attribute__((ext_vector_type(4))) __fp16 f16x4;
typedef __attribute__((ext_vector_type(2))) __fp16 h2_t;
typedef __attribute__((ext_vector_type(4))) float floatx4;

// ---------------------------------------------------------------- helpers
__device__ __forceinline__ void async_copy_16B(const void* g, void* l) {
  __builtin_amdgcn_global_load_lds(
      (const __attribute__((address_space(1))) void*)g,
      (__attribute__((address_space(3))) void*)l, 16, 0, 0);
}

// ---------------------------------------------------------------- prep
// Fused: cast x/w_in/w_out to f16 (5242880 float4s) and build packed f16
// weight-pair table wp[p][c], p=0..127:
//   p<126 : (w[p], w[p+1]) ; p==126 : (w[126], 0) ; p==127 : (0, w[0])
__global__ __launch_bounds__(256) void prep(
    const float* __restrict__ x, const float* __restrict__ w_in,
    const float* __restrict__ w_out, const float* __restrict__ w_dw,
    f16_t* __restrict__ x_h, f16_t* __restrict__ wi_h,
    f16_t* __restrict__ wo_h, h2_t* __restrict__ wp) {
  const int tid = blockIdx.x * 256 + threadIdx.x;
  if (tid < 5242880) {
    const float* src;
    f16_t* dst;
    int off;
    if (tid < 2097152) {
      src = x; dst = x_h; off = tid;
    } else if (tid < 4194304) {
      src = w_in; dst = wi_h; off = tid - 2097152;
    } else {
      src = w_out; dst = wo_h; off = tid - 4194304;
    }
    const float4 v = *(const float4*)(src + (size_t)off * 4);
    f16x4 o;
    o.x = (f16_t)v.x; o.y = (f16_t)v.y; o.z = (f16_t)v.z; o.w = (f16_t)v.w;
    *(f16x4*)(dst + (size_t)off * 4) = o;
  } else {
    const int idx = tid - 5242880;
    if (idx < 128 * 4096) {
      const int p = idx >> 12;
      const int c = idx & 4095;
      float a, b;
      if (p < 126) {
        a = w_dw[c * 127 + p]; b = w_dw[c * 127 + p + 1];
      } else if (p == 126) {
        a = w_dw[c * 127 + 126]; b = 0.f;
      } else {
        a = 0.f; b = w_dw[c * 127 + 0];
      }
      h2_t w;
      w.x = (f16_t)a; w.y = (f16_t)b;
      wp[idx] = w;
    }
  }
}

// ---------------------------------------------------------------- GEMM (NT)
// C[M,N] = A[M,K] * B[N,K]^T ; A,B f16 row-major, C = OutT row-major.
// BM=128 rows, BN_=128, BK=64 as two 32-col LDS panels. (GEMM1)
template <int BN_, typename OutT>
__global__ __launch_bounds__(256) void gemm_bt64(
    const f16_t* __restrict__ A, const f16_t* __restrict__ B,
    OutT* __restrict__ C, int M, int N, int K) {
  constexpr int BM_ = 128;
  constexpr int FI = (BN_ == 128) ? 4 : 2;
  constexpr int FJ = 4;
  constexpr int ACH = BM_ * 8;
  constexpr int CH = (BM_ + BN_) * 8;
  constexpr int CPT = CH / 256;

  __shared__ f16_t smem[(BM_ + BN_) * 64];
  f16_t* const As0 = smem;
  f16_t* const As1 = smem + BM_ * 32;
  f16_t* const Bs0 = smem + BM_ * 64;
  f16_t* const Bs1 = smem + BM_ * 64 + BN_ * 32;

  const int t = threadIdx.x;
  const int lane = t & 63;
  const int wave = t >> 6;
  const int m0 = blockIdx.y * BM_;
  const int n0 = blockIdx.x * BN_;
  const int wr = (BN_ == 128) ? (wave >> 1) * 64 : wave * 32;
  const int wc = (BN_ == 128) ? (wave & 1) * 64 : 0;
  const int fr = lane & 15;
  const int fk = (lane >> 4) * 8;

  floatx4 acc[FI][FJ] = {};

  const int kTiles = K / 64;
  for (int kt = 0; kt < kTiles; ++kt) {
    const int k0 = kt * 64;
    __syncthreads();
#pragma unroll
    for (int it = 0; it < CPT; ++it) {
      const int p = it * 256 + t;
      const f16_t* gsrc;
      if (p < BM_ * 4) {
        const int row = p >> 2, kc = (p & 3) * 8;
        gsrc = A + (size_t)(m0 + row) * K + k0 + kc;
      } else if (p < ACH) {
        const int q = p - BM_ * 4;
        const int row = q >> 2, kc = 32 + (q & 3) * 8;
        gsrc = A + (size_t)(m0 + row) * K + k0 + kc;
      } else if (p < ACH + BN_ * 4) {
        const int q = p - ACH;
        const int row = q >> 2, kc = (q & 3) * 8;
        gsrc = B + (size_t)(n0 + row) * K + k0 + kc;
      } else {
        const int q = p - ACH - BN_ * 4;
        const int row = q >> 2, kc = 32 + (q & 3) * 8;
        gsrc = B + (size_t)(n0 + row) * K + k0 + kc;
      }
      async_copy_16B(gsrc, smem + p * 8);
    }
    __syncthreads();

    f16x8 af[FI][2], bfr[FJ][2];
#pragma unroll
    for (int i = 0; i < FI; ++i) {
      const int r = (wr + i * 16 + fr) * 32 + fk;
      af[i][0] = *(const f16x8*)(As0 + r);
      af[i][1] = *(const f16x8*)(As1 + r);
    }
#pragma unroll
    for (int j = 0; j < FJ; ++j) {
      const int r = (wc + j * 16 + fr) * 32 + fk;
      bfr[j][0] = *(const f16x8*)(Bs0 + r);
      bfr[j][1] = *(const f16x8*)(Bs1 + r);
    }
#pragma unroll
    for (int h = 0; h < 2; ++h)
#pragma unroll
      for (int i = 0; i < FI; ++i)
#pragma unroll
        for (int j = 0; j < FJ; ++j)
          acc[i][j] = __builtin_amdgcn_mfma_f32_16x16x32_f16(
              af[i][h], bfr[j][h], acc[i][j], 0, 0, 0);
  }

  // C/D layout: col = lane&15, row = (lane>>4)*4 + reg
  const int cr = (lane >> 4) * 4;
  const int cc = lane & 15;
#pragma unroll
  for (int i = 0; i < FI; ++i)
#pragma unroll
    for (int j = 0; j < FJ; ++j)
#pragma unroll
      for (int r = 0; r < 4; ++r) {
        const int row = m0 + wr + i * 16 + cr + r;
        const int col = n0 + wc + j * 16 + cc;
        C[(size_t)row * N + col] = (OutT)acc[i][j][r];
      }
}

// ---------------------------------------------------------------- GEMM2
// BK=128 variant for the long-K (K=4096) out-projection: 4x 32-col panels,
// 48 KB LDS (3 blocks/CU), 32 K-tiles -> half the barrier drains of BK=64.
// BM=128, BN=64; wave w computes rows [w*32, w*32+32) x all 64 cols.
__global__ __launch_bounds__(256) void gemm_bt_k128(
    const f16_t* __restrict__ A, const f16_t* __restrict__ B,
    float* __restrict__ C, int M, int N, int K) {
  constexpr int BM_ = 128, BN_ = 64, KP = 4;
  constexpr int NA = BM_ * 4 * KP;            // 2048 A-chunks per K-tile
  constexpr int NTOT = (BM_ + BN_) * 4 * KP;  // 3072 chunks
  constexpr int CPT = NTOT / 256;             // 12

  __shared__ f16_t smem[(BM_ + BN_) * 128];  // 48 KB
  const int t = threadIdx.x;
  const int lane = t & 63;
  const int wave = t >> 6;
  const int m0 = blockIdx.y * BM_;
  const int n0 = blockIdx.x * BN_;
  const int wr = wave * 32;
  const int fr = lane & 15;
  const int fk = (lane >> 4) * 8;

  floatx4 acc[2][4] = {};

  const int kTiles = K / 128;
  for (int kt = 0; kt < kTiles; ++kt) {
    const int k0 = kt * 128;
    __syncthreads();
#pragma unroll
    for (int it = 0; it < CPT; ++it) {
      const int p = it * 256 + t;
      const f16_t* gsrc;
      if (p < NA) {
        const int h = p >> 9;               // panel 0..3
        const int r = (p >> 2) & (BM_ - 1);
        const int kc = h * 32 + (p & 3) * 8;
        gsrc = A + (size_t)(m0 + r) * K + k0 + kc;
      } else {
        const int q = p - NA;
        const int h = q >> 8;
        const int r = (q >> 2) & (BN_ - 1);
        const int kc = h * 32 + (q & 3) * 8;
        gsrc = B + (size_t)(n0 + r) * K + k0 + kc;
      }
      async_copy_16B(gsrc, smem + p * 8);
    }
    __syncthreads();

#pragma unroll
    for (int h = 0; h < KP; ++h) {
      f16x8 af[2], bf[4];
#pragma unroll
      for (int i = 0; i < 2; ++i)
        af[i] = *(const f16x8*)(smem + h * BM_ * 32 + (wr + i * 16 + fr) * 32 + fk);
#pragma unroll
      for (int j = 0; j < 4; ++j)
        bf[j] = *(const f16x8*)(smem + NA * 8 + h * BN_ * 32 + (j * 16 + fr) * 32 + fk);
#pragma unroll
      for (int i = 0; i < 2; ++i)
#pragma unroll
        for (int j = 0; j < 4; ++j)
          acc[i][j] = __builtin_amdgcn_mfma_f32_16x16x32_f16(
              af[i], bf[j], acc[i][j], 0, 0, 0);
    }
  }

  const int cr = (lane >> 4) * 4;
  const int cc = lane & 15;
#pragma unroll
  for (int i = 0; i < 2; ++i)
#pragma unroll
    for (int j = 0; j < 4; ++j)
#pragma unroll
      for (int r = 0; r < 4; ++r) {
        const int row = m0 + wr + i * 16 + cr + r;
        const int col = n0 + j * 16 + cc;
        C[(size_t)row * N + col] = acc[i][j][r];
      }
}

// ---------------------------------------------------------------- conv+gate
// vg: [8192][8192] f16 (v = cols 0..4095, g = cols 4096..8191)
// wp: [128][4096] packed f16 weight pairs ; y: [8192][4096] f16
// Block: 64 channels x 128 l-outputs; 4 waves x 32 l's, lane=channel.
// All operands LDS-resident with immediate ds offsets; g gate values
// preloaded into registers BEFORE the FIR loop so their ~400cyc L3 latency
// hides under ~5000cyc of fdot2 issue.
#define CONV_L 128
#define CPAIRS 127  // (CONV_L + 126) / 2

__global__ __launch_bounds__(256) void conv_gate(
    const f16_t* __restrict__ vg, const h2_t* __restrict__ wp,
    const float* __restrict__ b_dw, f16_t* __restrict__ y) {
  __shared__ uint32_t vtp[CPAIRS * 64];  // 32.5 KB
  __shared__ uint32_t wpl[128 * 64];     // 32 KB
  const int t = threadIdx.x;
  const int lane = t & 63;
  const int wave = t >> 6;
  const int c0 = blockIdx.x * 64;
  const int lt = blockIdx.y & 31;   // 4096/128 l-tiles
  const int b = blockIdx.y >> 5;
  const int l0 = lt * CONV_L;

  // stage weight pairs wp[p][c0..c0+63] -> wpl via global->LDS DMA
#pragma unroll
  for (int it = 0; it < 8; ++it) {
    const int q = it * 256 + t;  // 2048 16B chunks: row = q>>4, 4 words each
    async_copy_16B(wp + (size_t)(q >> 4) * 4096 + c0 + (q & 15) * 4,
                   wpl + q * 4);
  }
  // stage v rows [l0-126, l0+127] pair-interleaved (zeros for l<0)
  for (int q = t; q < CPAIRS * 8; q += 256) {
    const int m = q >> 3;
    const int oc = (q & 7) * 8;
    const int le = l0 - 126 + 2 * m;  // always even
    uint4 a = make_uint4(0u, 0u, 0u, 0u);
    uint4 bb = make_uint4(0u, 0u, 0u, 0u);
    if (le >= 0) {
      const size_t base = (size_t)(b * 4096 + le) * 8192 + c0 + oc;
      a = *(const uint4*)(vg + base);
      bb = *(const uint4*)(vg + base + 8192);
    }
    uint32_t* dst = vtp + m * 64 + oc;
    const uint32_t aw[4] = {a.x, a.y, a.z, a.w};
    const uint32_t bw[4] = {bb.x, bb.y, bb.z, bb.w};
#pragma unroll
    for (int i = 0; i < 4; ++i) {
      dst[2 * i] = (aw[i] & 0xFFFFu) | (bw[i] << 16);
      dst[2 * i + 1] = (aw[i] >> 16) | (bw[i] & 0xFFFF0000u);
    }
  }

  const int c = c0 + lane;
  const int lb = l0 + wave * 32;
  // preload gate values (independent of LDS staging; latency hidden by FIR)
  const f16_t* gp = vg + (size_t)(b * 4096 + lb) * 8192 + 4096 + c;
  f16_t gvals[32];
#pragma unroll
  for (int i = 0; i < 32; ++i) gvals[i] = gp[(size_t)i * 8192];

  __syncthreads();

  const float bias = b_dw[c];
  float acc[32];
#pragma unroll
  for (int i = 0; i < 32; ++i) acc[i] = bias;

  // single-base immediate-offset LDS pointers
  const uint32_t* vbase = vtp + wave * 16 * 64 + lane;  // pair index of v[r0]
  const uint32_t* wbase = wpl + lane;

  // ring slot m holds pair (v[r0+2m], v[r0+2m+1]); slots 0..16
  h2_t ring[17];
#pragma unroll
  for (int m = 0; m < 17; ++m)
    ring[m] = __builtin_bit_cast(h2_t, vbase[m * 64]);

  // tap 0 for odd outputs: weight (0, w[0]) = wpl row 127
  {
    const h2_t w0 = __builtin_bit_cast(h2_t, wbase[127 * 64]);
#pragma unroll
    for (int h = 0; h < 16; ++h)
      acc[2 * h + 1] =
          __builtin_amdgcn_fdot2(w0, ring[h], acc[2 * h + 1], false);
  }

  // step k: even outs use row 2k (taps 2k,2k+1); odd outs row 2k+1
#pragma unroll
  for (int k = 0; k < 64; ++k) {
    const h2_t we = __builtin_bit_cast(h2_t, wbase[(2 * k) * 64]);
#pragma unroll
    for (int h = 0; h < 16; ++h)
      acc[2 * h] =
          __builtin_amdgcn_fdot2(we, ring[(k + h) % 17], acc[2 * h], false);
    if (k < 63) {
      const h2_t wo = __builtin_bit_cast(h2_t, wbase[(2 * k + 1) * 64]);
#pragma unroll
      for (int h = 0; h < 16; ++h)
        acc[2 * h + 1] = __builtin_amdgcn_fdot2(wo, ring[(k + 1 + h) % 17],
                                                acc[2 * h + 1], false);
      if (k < 62)  // slide: slot k%17 <- pair k+17
        ring[k % 17] = __builtin_bit_cast(h2_t, vbase[(17 + k) * 64]);
    }
  }

  f16_t* yp = y + (size_t)(b * 4096 + lb) * 4096 + c;
#pragma unroll
  for (int i = 0; i < 32; ++i) {
    const float gv = (float)gvals[i];
    const float v = acc[i];
    const float sv = v / (1.f + __expf(-v));
    const float sg = gv / (1.f + __expf(-gv));
    yp[(size_t)i * 4096] = (f16_t)(sv * sg);
  }
}

// ---------------------------------------------------------------- launch
extern "C" void kernel_launch(void* const* d_in, const int* in_sizes, int n_in,
                              void* d_out, int out_size, void* d_ws,
                              size_t ws_size, hipStream_t stream) {
  const float* x     = (const float*)d_in[0];  // [2,4096,1024]
  const float* w_in  = (const float*)d_in[1];  // [8192,1024]
  const float* w_dw  = (const float*)d_in[2];  // [4096,127]
  const float* b_dw  = (const float*)d_in[3];  // [4096]
  const float* w_out = (const float*)d_in[4];  // [1024,4096]
  float* out = (float*)d_out;                  // [2,4096,1024]

  char* p = (char*)d_ws;
  f16_t* x_h  = (f16_t*)p; p += (size_t)8192 * 1024 * 2;
  f16_t* wi_h = (f16_t*)p; p += (size_t)8192 * 1024 * 2;
  f16_t* wo_h = (f16_t*)p; p += (size_t)1024 * 4096 * 2;
  h2_t*  wp   = (h2_t*)p;  p += (size_t)128 * 4096 * 4;
  f16_t* vg   = (f16_t*)p; p += (size_t)8192 * 8192 * 2;
  f16_t* y    = (f16_t*)p; p += (size_t)8192 * 4096 * 2;

  // fused casts + packed weight-pair build
  prep<<<22528, 256, 0, stream>>>(x, w_in, w_out, w_dw, x_h, wi_h, wo_h, wp);

  // vg[8192,8192] = x[8192,1024] @ w_in[8192,1024]^T
  gemm_bt64<128, f16_t><<<dim3(64, 64), 256, 0, stream>>>(x_h, wi_h, vg,
                                                          8192, 8192, 1024);
  // y = silu(causal_dwconv(v)+b) * silu(g)
  conv_gate<<<dim3(64, 64), 256, 0, stream>>>(vg, wp, b_dw, y);
  // out[8192,1024] = y[8192,4096] @ w_out[1024,4096]^T (BK=128, 3 blk/CU)
  gemm_bt_k128<<<dim3(16, 64), 256, 0, stream>>>(y, wo_h, out,
                                                 8192, 1024, 4096);
}